// Round 7
// baseline (692.237 us; speedup 1.0000x reference)
//
#include <hip/hip_runtime.h>

// V=5000, C=128, K=64. 3 launches: init, fused_prep (16 blocks persistent), cg+finish.
// Math (R5/R6-proven): Mx-congruence basis; op'(W) = E W H + LMB[W Q0 - Dr W Qr - Di W Qi],
// E = Ahat Ahat^T + LMB diag(r1r^2+r1i^2), Ahat = Mx^T A, H = My^T My, rhs = Ahat B0^T H.
// chol(E)/chol(H) congruence -> At(Y) = Y + sum_{t=1..3} L_t Y R_t ; pipelined CG (GV).
// R7 split rationale: R5's standalone CG measured 1.59us/iter (fetch-add barrier +
// atomicAdd reductions + L1-cacheable operator reads); R6's fused CG ran ~3.7us/iter.
#define NV 5000
#define LMB 100.0f
#define MAXIT 150
#define TOL 1e-10f
#define NBLK 16

// ---- workspace float offsets ----
#define SV_O    0
#define PART_O  256
#define AH_O    131328
#define B0_O    139520
#define H_O     147712
#define E_O     151808
#define Z2_O    155904
#define RH_O    160000
#define Q0_O    164096
#define LIH_O   176384
#define LIE_O   180480
#define U0_O    184576
#define QT0_O   196864
#define E0_O    209152
#define TB_O    221440
#define BT_O    225536
#define RSTK_O  229632
#define LCT_O   246016
#define WG_O    262400
#define XG_O    266496
#define CTRL_O  270592   // ints: prep flags [blk*32], go [512], cg cnt [600]; floats RZ @+640, PQ @+840
#define WS_NEED 276544

__device__ __forceinline__ float aload(const float* p) {
  return __hip_atomic_load(p, __ATOMIC_RELAXED, __HIP_MEMORY_SCOPE_AGENT);
}
__device__ __forceinline__ void astore(float* p, float v) {
  __hip_atomic_store(p, v, __ATOMIC_RELAXED, __HIP_MEMORY_SCOPE_AGENT);
}

__global__ void init_kernel(float* ctrl) {
  int e = threadIdx.x;
#pragma unroll
  for (int u = 0; u < 4; ++u) ctrl[u * 256 + e] = 0.f;
}

// ---- flag-tree barrier (prep only; proven R6) ----
__device__ __forceinline__ void gbar2(int* ctrl, int blk, int bt) {
  __syncthreads();
  int tid = threadIdx.x;
  if (blk == 0) {
    if (tid > 0 && tid < NBLK) {
      while (__hip_atomic_load(&ctrl[tid * 32], __ATOMIC_ACQUIRE, __HIP_MEMORY_SCOPE_AGENT) < bt)
        __builtin_amdgcn_s_sleep(1);
    }
    __syncthreads();
    if (tid == 0)
      __hip_atomic_store(&ctrl[512], bt, __ATOMIC_RELEASE, __HIP_MEMORY_SCOPE_AGENT);
  } else {
    if (tid == 0) {
      __hip_atomic_store(&ctrl[blk * 32], bt, __ATOMIC_RELEASE, __HIP_MEMORY_SCOPE_AGENT);
      while (__hip_atomic_load(&ctrl[512], __ATOMIC_ACQUIRE, __HIP_MEMORY_SCOPE_AGENT) < bt)
        __builtin_amdgcn_s_sleep(1);
    }
  }
  __syncthreads();
}

// ---- fetch-add barrier (CG; proven R5) ----
__device__ __forceinline__ void gbar(int* cnt, int target) {
  __syncthreads();
  if (threadIdx.x == 0) {
    __hip_atomic_fetch_add(cnt, 1, __ATOMIC_ACQ_REL, __HIP_MEMORY_SCOPE_AGENT);
    while (__hip_atomic_load(cnt, __ATOMIC_ACQUIRE, __HIP_MEMORY_SCOPE_AGENT) < target) {
      __builtin_amdgcn_s_sleep(2);
    }
  }
  __syncthreads();
}

__device__ __forceinline__ void red_atomic(float v, float* red, float* dst) {
  int tid = threadIdx.x;
  red[tid] = v;
  __syncthreads();
  if (tid < 128) red[tid] += red[tid + 128];
  __syncthreads();
  if (tid < 64) {
    float s = red[tid] + red[tid + 64];
#pragma unroll
    for (int o = 32; o > 0; o >>= 1) s += __shfl_down(s, o, 64);
    if (tid == 0) atomicAdd(dst, s);
  }
  __syncthreads();
}

// ---- LDS staging + 64x64 GEMM helpers ----
__device__ __forceinline__ void stageN(float* dst, const float* src) {
  for (int e = threadIdx.x; e < 4096; e += 256)
    dst[(e >> 6) * 65 + (e & 63)] = aload(src + e);
}
__device__ __forceinline__ void stageT(float* dst, const float* src) {
  for (int e = threadIdx.x; e < 4096; e += 256)
    dst[(e & 63) * 65 + (e >> 6)] = aload(src + e);
}
__device__ __forceinline__ void mm65(const float* Ls, const float* Rs, float* D) {
  for (int e = threadIdx.x; e < 4096; e += 256) {
    int i = e >> 6, j = e & 63;
    float acc = 0.f;
#pragma unroll 8
    for (int t = 0; t < 64; ++t) acc = fmaf(Ls[i * 65 + t], Rs[t * 65 + j], acc);
    astore(D + e, acc);
  }
}
__device__ void mmNN_s(const float* L, const float* R, float* D, float* sm) {
  stageN(sm, L); stageN(sm + 4160, R);
  __syncthreads();
  mm65(sm, sm + 4160, D);
}
__device__ void mmNT_s(const float* L, const float* R, float* D, float* sm) {
  stageN(sm, L); stageT(sm + 4160, R);
  __syncthreads();
  mm65(sm, sm + 4160, D);
}

// ---- 64x64 SPD Cholesky + explicit L^-1 ----
__device__ void chol_inv(const float* S, float* Li, float* sm) {
  float (*M)[65] = (float (*)[65])sm;
  float (*T)[65] = (float (*)[65])(sm + 64 * 65);
  int tid = threadIdx.x;
  for (int e = tid; e < 4096; e += 256) {
    M[e >> 6][e & 63] = aload(S + e);
    T[e >> 6][e & 63] = 0.f;
  }
  __syncthreads();
  for (int j = 0; j < 64; ++j) {
    float pv = M[j][j];
    __syncthreads();
    float sc = rsqrtf(pv);
    if (tid < 64 - j) M[j + tid][j] *= sc;
    __syncthreads();
    int m = 63 - j, c2 = (m * (m + 1)) >> 1;
    for (int e = tid; e < c2; e += 256) {
      int rp = (int)((sqrtf(8.f * (float)e + 1.f) - 1.f) * 0.5f);
      while (((rp + 1) * (rp + 2)) >> 1 <= e) ++rp;
      while ((rp * (rp + 1)) >> 1 > e) --rp;
      int cp = e - ((rp * (rp + 1)) >> 1);
      int r = j + 1 + rp, c = j + 1 + cp;
      M[r][c] = fmaf(-M[r][j], M[c][j], M[r][c]);
    }
    __syncthreads();
  }
  if (tid < 64) {
    int c = tid;
    T[c][c] = 1.f / M[c][c];
    for (int r = c + 1; r < 64; ++r) {
      float s = 0.f;
      for (int t = c; t < r; ++t) s = fmaf(M[r][t], T[t][c], s);
      T[r][c] = -s / M[r][r];
    }
  }
  __syncthreads();
  for (int e = tid; e < 4096; e += 256) astore(Li + e, T[e >> 6][e & 63]);
}

// ---- partial projection ----
__device__ void proj_seg(const float* P, const float* f, float* Opart, float* sm) {
  float* Pl = sm;  // [64][126]
  int tid = threadIdx.x;
  int rg = (tid >> 5) << 3;
  int cq = (tid & 31) << 2;
  float acc[8][4];
#pragma unroll
  for (int u = 0; u < 8; ++u)
#pragma unroll
    for (int v = 0; v < 4; ++v) acc[u][v] = 0.f;
  for (int t5 = 0; t5 < 5; ++t5) {
    int vb = t5 * 125;
    __syncthreads();
    for (int e = tid; e < 8000; e += 256) {
      int rr = e / 125, vv = e - rr * 125;
      Pl[rr * 126 + vv] = P[rr * NV + vb + vv];
    }
    __syncthreads();
    for (int vv = 0; vv < 125; ++vv) {
      float4 fv = *(const float4*)(f + (vb + vv) * 128 + cq);
#pragma unroll
      for (int u = 0; u < 8; ++u) {
        float pv = Pl[(rg + u) * 126 + vv];
        acc[u][0] = fmaf(pv, fv.x, acc[u][0]);
        acc[u][1] = fmaf(pv, fv.y, acc[u][1]);
        acc[u][2] = fmaf(pv, fv.z, acc[u][2]);
        acc[u][3] = fmaf(pv, fv.w, acc[u][3]);
      }
    }
  }
#pragma unroll
  for (int u = 0; u < 8; ++u)
#pragma unroll
    for (int v = 0; v < 4; ++v) astore(Opart + (rg + u) * 128 + cq + v, acc[u][v]);
}

// ================= fused prep (R6 P0-P5 verbatim) =================
__global__ __launch_bounds__(256) void fused_prep_kernel(
    const float* fx, const float* fy, const float* ex, const float* ey,
    const float* Px, const float* Py, const float* Mx, const float* My, float* W) {
  __shared__ float sm[10752];
  int tid = threadIdx.x, blk = blockIdx.x;
  int* ctrl = (int*)(W + CTRL_O);
  int bt = 0;

  // P0: sv + projection partials
  if (blk == 0 && tid < 64) {
    float vx = ex[tid], vy = ey[tid];
    float m = fmaxf(vx, vy);
#pragma unroll
    for (int o = 32; o > 0; o >>= 1) m = fmaxf(m, __shfl_xor(m, o, 64));
    float g1 = sqrtf(vx / m), g2 = sqrtf(vy / m);   // GAMMA = 0.5
    float d1 = 1.f / fmaf(g1, g1, 1.f), d2 = 1.f / fmaf(g2, g2, 1.f);
    astore(W + SV_O + tid, g1 * d1);
    astore(W + SV_O + 64 + tid, d1);
    astore(W + SV_O + 128 + tid, g2 * d2);
    astore(W + SV_O + 192 + tid, d2);
  }
  {
    int mat = blk & 1, seg = blk >> 1;
    const float* P = mat ? Py : Px;
    const float* f = mat ? fy : fx;
    proj_seg(P + seg * 625, f + (size_t)seg * 625 * 128, W + PART_O + blk * 8192, sm);
  }
  gbar2(ctrl, blk, ++bt);

  // P1: Ahat = Mx^T A fused-reduce (0-3), B0 reduce (4-7), H (8-15)
  if (blk < 4) {
    int c0 = blk * 32;
    for (int e = tid; e < 2048; e += 256) {
      int t = e >> 5, cl = e & 31;
      float s = 0.f;
#pragma unroll
      for (int p = 0; p < 8; ++p) s += aload(W + PART_O + (2 * p) * 8192 + t * 128 + c0 + cl);
      sm[t * 33 + cl] = s;
    }
    __syncthreads();
    for (int e = tid; e < 2048; e += 256) {
      int i = e >> 5, cl = e & 31;
      float acc = 0.f;
      for (int t = 0; t < 64; ++t) acc = fmaf(Mx[t * 64 + i], sm[t * 33 + cl], acc);
      astore(W + AH_O + i * 128 + c0 + cl, acc);
    }
  } else if (blk < 8) {
    int base = (blk - 4) * 2048;
    for (int e = tid; e < 2048; e += 256) {
      float s = 0.f;
#pragma unroll
      for (int p = 0; p < 8; ++p) s += aload(W + PART_O + (2 * p + 1) * 8192 + base + e);
      astore(W + B0_O + base + e, s);
    }
  } else {
    int base = (blk - 8) * 512;
    for (int e = tid; e < 512; e += 256) {
      int i = (base + e) >> 6, j = (base + e) & 63;
      float acc = 0.f;
      for (int t = 0; t < 64; ++t) acc = fmaf(My[t * 64 + i], My[t * 64 + j], acc);
      astore(W + H_O + base + e, acc);
    }
  }
  gbar2(ctrl, blk, ++bt);

  // P2: E (0-3), Z2 (4-7), chol(H) (8), Q* (9-11)
  if (blk < 4) {
    for (int e = tid; e < 8192; e += 256) {
      int i = e >> 7, c = e & 127;
      sm[c * 65 + i] = aload(W + AH_O + e);
    }
    __syncthreads();
    int i0 = blk * 16;
    for (int e = tid; e < 1024; e += 256) {
      int i = i0 + (e >> 6), j = e & 63;
      float acc = 0.f;
#pragma unroll 8
      for (int c = 0; c < 128; ++c) acc = fmaf(sm[c * 65 + i], sm[c * 65 + j], acc);
      if (i == j) {
        float a = aload(W + SV_O + i), b = aload(W + SV_O + 64 + i);
        acc += LMB * (a * a + b * b);
      }
      astore(W + E_O + i * 64 + j, acc);
    }
  } else if (blk < 8) {
    int i0 = (blk - 4) * 16;
    for (int e = tid; e < 8192; e += 256) {
      int j = e >> 7, c = e & 127;
      sm[c * 65 + j] = aload(W + B0_O + e);
    }
    for (int e = tid; e < 2048; e += 256) {
      int il = e >> 7, c = e & 127;
      sm[8320 + c * 17 + il] = aload(W + AH_O + (i0 + il) * 128 + c);
    }
    __syncthreads();
    for (int e = tid; e < 1024; e += 256) {
      int il = e >> 6, j = e & 63;
      float acc = 0.f;
#pragma unroll 8
      for (int c = 0; c < 128; ++c) acc = fmaf(sm[8320 + c * 17 + il], sm[c * 65 + j], acc);
      astore(W + Z2_O + (i0 + il) * 64 + j, acc);
    }
  } else if (blk == 8) {
    chol_inv(W + H_O, W + LIH_O, sm);
  } else if (blk <= 11) {
    if (tid < 256) sm[tid] = aload(W + SV_O + tid);
    __syncthreads();
    int t = blk - 9;
    for (int e = tid; e < 4096; e += 256) {
      int k = e >> 6, b = e & 63;
      float h = aload(W + H_O + e), v;
      if (t == 0) v = h * (sm[128 + k] * sm[128 + b] + sm[192 + k] * sm[192 + b]);
      else if (t == 1) v = h * (sm[128 + k] + sm[128 + b]);
      else v = h * (sm[192 + k] + sm[192 + b]);
      astore(W + Q0_O + t * 4096 + e, v);
    }
  }
  gbar2(ctrl, blk, ++bt);

  // P3: chol(E) (0), RH = Z2 H (1), U* = LiH Q* (2-4)
  if (blk == 0) chol_inv(W + E_O, W + LIE_O, sm);
  else if (blk == 1) mmNN_s(W + Z2_O, W + H_O, W + RH_O, sm);
  else if (blk <= 4) mmNN_s(W + LIH_O, W + Q0_O + (blk - 2) * 4096, W + U0_O + (blk - 2) * 4096, sm);
  gbar2(ctrl, blk, ++bt);

  // P4: TB (0), QT* (1-3), E0 (4), Er/Ei (5-6)
  if (blk == 0) mmNN_s(W + LIE_O, W + RH_O, W + TB_O, sm);
  else if (blk <= 3) mmNT_s(W + U0_O + (blk - 1) * 4096, W + LIH_O, W + QT0_O + (blk - 1) * 4096, sm);
  else if (blk == 4) mmNT_s(W + LIE_O, W + LIE_O, W + E0_O, sm);
  else if (blk <= 6) {
    if (tid < 64) sm[8320 + tid] = aload(W + SV_O + ((blk == 5) ? tid : 64 + tid));
    __syncthreads();
    stageN(sm, W + LIE_O);
    for (int e = tid; e < 4096; e += 256) {
      int j = e >> 6, k = e & 63;
      sm[4160 + k * 65 + j] = aload(W + LIE_O + e) * sm[8320 + k];
    }
    __syncthreads();
    mm65(sm, sm + 4160, W + E0_O + (blk - 4) * 4096);
  }
  gbar2(ctrl, blk, ++bt);

  // P5: BT (0), RSTK pack (1-2), LCT pack (3-4)
  if (blk == 0) mmNT_s(W + TB_O, W + LIH_O, W + BT_O, sm);
  else if (blk <= 2) {
    for (int tt = 0; tt < 2; ++tt) {
      int t = (blk - 1) * 2 + tt;
      if (t == 0) {
        for (int e = tid; e < 4096; e += 256)
          astore(W + RSTK_O + e, ((e >> 6) == (e & 63)) ? 1.f : 0.f);
      } else {
        stageN(sm, W + QT0_O + (t - 1) * 4096);
        __syncthreads();
        for (int e = tid; e < 4096; e += 256) {
          int a = e >> 6, b = e & 63;
          astore(W + RSTK_O + t * 4096 + e, 0.5f * (sm[a * 65 + b] + sm[b * 65 + a]));
        }
        __syncthreads();
      }
    }
  } else if (blk <= 4) {
    for (int tt = 0; tt < 2; ++tt) {
      int t = (blk - 3) * 2 + tt;
      if (t == 0) {
        for (int e = tid; e < 4096; e += 256)
          astore(W + LCT_O + e, ((e >> 6) == (e & 63)) ? 1.f : 0.f);
      } else {
        float sgn = (t == 1) ? LMB : -LMB;
        stageN(sm, W + E0_O + (t - 1) * 4096);
        __syncthreads();
        for (int e = tid; e < 4096; e += 256) {
          int k = e >> 6, i = e & 63;
          astore(W + LCT_O + t * 4096 + e, sgn * 0.5f * (sm[k * 65 + i] + sm[i * 65 + k]));
        }
        __syncthreads();
      }
    }
  }
  // kernel end = device-wide visibility for next launch
}

// ---- trimmed apply: At(Y) = Y + sum_{t=1..3} L_t (Y R_t) ----
__device__ __forceinline__ float at_apply3(const float (*pT)[68], const float* Rown,
                                           float* Tt, const float* LCT1,
                                           int lane, int wv, int jown) {
  if (wv >= 1) {
    const float* R0 = Rown + (wv - 1) * 256;
    float a0 = 0.f, a1 = 0.f, a2 = 0.f, a3 = 0.f;
    for (int m = 0; m < 64; ++m) {
      float pv = pT[m][lane];
      a0 = fmaf(pv, R0[m], a0);
      a1 = fmaf(pv, R0[64 + m], a1);
      a2 = fmaf(pv, R0[128 + m], a2);
      a3 = fmaf(pv, R0[192 + m], a3);
    }
    Tt[0 * 192 + (wv - 1) * 64 + lane] = a0;
    Tt[1 * 192 + (wv - 1) * 64 + lane] = a1;
    Tt[2 * 192 + (wv - 1) * 64 + lane] = a2;
    Tt[3 * 192 + (wv - 1) * 64 + lane] = a3;
  }
  __syncthreads();
  const float* Lc = LCT1 + lane;
  const float* Tw = Tt + wv * 192;
  float b0 = 0.f, b1 = 0.f, b2 = 0.f, b3 = 0.f;
  for (int tk = 0; tk < 192; tk += 4) {
    b0 = fmaf(Lc[(tk + 0) * 64], Tw[tk + 0], b0);
    b1 = fmaf(Lc[(tk + 1) * 64], Tw[tk + 1], b1);
    b2 = fmaf(Lc[(tk + 2) * 64], Tw[tk + 2], b2);
    b3 = fmaf(Lc[(tk + 3) * 64], Tw[tk + 3], b3);
  }
  return pT[jown][lane] + (b0 + b1) + (b2 + b3);
}

// ================= pipelined CG (R5 structure) + finish =================
__global__ __launch_bounds__(256) void cg_kernel(const float* Mx, float* W, float* out) {
  __shared__ float sm[8704];
  __shared__ float red[256];
  __shared__ float scal[3];
  int tid = threadIdx.x, blk = blockIdx.x;
  int lane = tid & 63, wv = tid >> 6;
  int j0 = blk * 4, jown = j0 + wv;
  float (*pT)[68] = (float (*)[68])sm;
  float* Rown = sm + 4352;
  float* Tt = sm + 5120;
  const float* BT = W + BT_O;
  const float* RSTK = W + RSTK_O;
  const float* LCT1 = W + LCT_O + 4096;   // skip t=0 identity
  float* wg = W + WG_O;
  int* cnt = (int*)(W + CTRL_O) + 600;
  float* RZ = W + CTRL_O + 640;
  float* PQ = W + CTRL_O + 840;

  for (int e = tid; e < 768; e += 256) {
    int t = e >> 8, jl = (e >> 6) & 3, m = e & 63;
    Rown[t * 256 + jl * 64 + m] = RSTK[((t + 1) * 64 + j0 + jl) * 64 + m];
  }
  for (int u = 0; u < 16; ++u) {
    int g = u * 256 + tid;               // g = col*64+row
    pT[g >> 6][g & 63] = BT[(g & 63) * 64 + (g >> 6)];
  }
  __syncthreads();
  float w_l = at_apply3(pT, Rown, Tt, LCT1, lane, wv, jown);
  float r_l = BT[lane * 64 + jown];
  astore(&wg[jown * 64 + lane], w_l);
  red_atomic(r_l * r_l, red, &RZ[0]);
  red_atomic(w_l * r_l, red, &PQ[0]);
  int bt = 0;
  gbar(cnt, (++bt) * NBLK);

  float p_l = 0.f, q_l = 0.f, z_l = 0.f, x_l = 0.f;
  float gprev = 1.f, aprev = 1.f;
  for (int j = 0; j < MAXIT; ++j) {
    if (tid == 0) {
      scal[0] = aload(&RZ[j]);
      scal[1] = aload(&PQ[j]);
      scal[2] = aload(&RZ[0]);
    }
    __syncthreads();
    float gj = scal[0], dj = scal[1], g0 = scal[2];
    if (j > 0 && gj < TOL * g0) break;
    float bj = (j == 0) ? 0.f : gj / gprev;
    float aj = (j == 0) ? gj / dj : gj / (dj - bj * gj / aprev);
    for (int u = 0; u < 16; ++u) {
      int g = u * 256 + tid;
      pT[g >> 6][g & 63] = aload(&wg[g]);
    }
    __syncthreads();
    float n_l = at_apply3(pT, Rown, Tt, LCT1, lane, wv, jown);
    z_l = fmaf(bj, z_l, n_l);
    q_l = fmaf(bj, q_l, w_l);
    p_l = fmaf(bj, p_l, r_l);
    x_l = fmaf(aj, p_l, x_l);
    r_l = fmaf(-aj, q_l, r_l);
    w_l = fmaf(-aj, z_l, w_l);
    astore(&wg[jown * 64 + lane], w_l);
    red_atomic(r_l * r_l, red, &RZ[j + 1]);
    red_atomic(w_l * r_l, red, &PQ[j + 1]);
    gprev = gj; aprev = aj;
    gbar(cnt, (++bt) * NBLK);
  }
  astore(&W[XG_O + jown * 64 + lane], x_l);   // Y col-major
  gbar(cnt, (++bt) * NBLK);

  // ---- finish (block 0): out = (Mx LiE^T Y LiH)^T ----
  if (blk == 0) {
    float* Ys = sm;           // [64][65]
    float* Ms2 = sm + 4160;   // [64][65]
    for (int e = tid; e < 4096; e += 256) Ys[(e >> 6) * 65 + (e & 63)] = aload(W + XG_O + e);
    for (int e = tid; e < 4096; e += 256) Ms2[(e >> 6) * 65 + (e & 63)] = W[LIE_O + e];
    __syncthreads();
    for (int e = tid; e < 4096; e += 256) {   // V1 = LiE^T Y  (Ys[j][i] = Y[i][j])
      int t = e >> 6, b = e & 63;
      float acc = 0.f;
#pragma unroll 8
      for (int a = 0; a < 64; ++a) acc = fmaf(Ms2[a * 65 + t], Ys[b * 65 + a], acc);
      W[WG_O + t * 64 + b] = acc;
    }
    __syncthreads();
    for (int e = tid; e < 4096; e += 256) Ys[(e >> 6) * 65 + (e & 63)] = W[WG_O + e];
    for (int e = tid; e < 4096; e += 256) Ms2[(e >> 6) * 65 + (e & 63)] = W[LIH_O + e];
    __syncthreads();
    for (int e = tid; e < 4096; e += 256) {   // WH = V1 LiH
      int t = e >> 6, c = e & 63;
      float acc = 0.f;
#pragma unroll 8
      for (int b = 0; b < 64; ++b) acc = fmaf(Ys[t * 65 + b], Ms2[b * 65 + c], acc);
      W[WG_O + t * 64 + c] = acc;
    }
    __syncthreads();
    for (int e = tid; e < 4096; e += 256) Ys[(e >> 6) * 65 + (e & 63)] = W[WG_O + e];
    for (int e = tid; e < 4096; e += 256) Ms2[(e & 63) * 65 + (e >> 6)] = Mx[e];
    __syncthreads();
    for (int e = tid; e < 4096; e += 256) {   // out[r][c] = sum_t Mx[c][t] WH[t][r]
      int r = e >> 6, c = e & 63;
      float acc = 0.f;
#pragma unroll 8
      for (int t = 0; t < 64; ++t) acc = fmaf(Ms2[t * 65 + c], Ys[t * 65 + r], acc);
      out[e] = acc;
    }
  }
}

extern "C" void kernel_launch(void* const* d_in, const int* in_sizes, int n_in,
                              void* d_out, int out_size, void* d_ws, size_t ws_size,
                              hipStream_t stream) {
  const float* fx = (const float*)d_in[0];
  const float* fy = (const float*)d_in[1];
  const float* ex = (const float*)d_in[2];
  const float* ey = (const float*)d_in[3];
  const float* Px = (const float*)d_in[4];
  const float* Py = (const float*)d_in[5];
  const float* Mx = (const float*)d_in[6];
  const float* My = (const float*)d_in[7];
  float* out = (float*)d_out;
  float* W = (float*)d_ws;

  if (ws_size < (size_t)WS_NEED * sizeof(float)) {
    hipMemsetAsync(d_out, 0, (size_t)out_size * sizeof(float), stream);
    return;
  }

  init_kernel<<<1, 256, 0, stream>>>(W + CTRL_O);
  fused_prep_kernel<<<NBLK, 256, 0, stream>>>(fx, fy, ex, ey, Px, Py, Mx, My, W);
  cg_kernel<<<NBLK, 256, 0, stream>>>(Mx, W, out);
}

// Round 8
// 505.410 us; speedup vs baseline: 1.3697x; 1.3697x over previous
//
#include <hip/hip_runtime.h>

// V=5000, C=128, K=64. 7 launches. Math (R5/R7-proven): Mx-congruence basis;
// E = Ahat Ahat^T + LMB diag(r1r^2+r1i^2), Ahat = Mx^T A, H = My^T My;
// chol(E)/chol(H) congruence -> At(Y) = Y + sum_{t=0..2} L_t Y R_t, solve by
// pipelined Jacobi-PCG (Ghysels-Vanroose, 1 barrier/iter, M^-1 elementwise-free).
// R7 lesson: prep was latency-bound (atomics bypass L1; no ILP); here prep uses
// ONLY plain memory (kernel boundaries provide visibility) + explicit load batching.
#define NV 5000
#define LMB 100.0f
#define MAXIT 150
#define TOL 1e-10f
#define NBLK 16

// ---- workspace float offsets ----
#define SV_O     0
#define CTRL_O   256      // int cnt @0; RZ floats @+64 (151); PQ @+264 (151); zeroed in K1
#define PART_O   2048     // 80 * 8192
#define AH_O     657408
#define B0_O     665600
#define H_O      673792
#define E_O      677888
#define Z2_O     681984
#define RH_O     686080
#define Q0_O     690176   // Q0,QR,QI contiguous (3*4096)
#define LIH_O    702464
#define LIE_O    706560
#define U0_O     710656   // 3*4096
#define QT0_O    722944   // 3*4096
#define E0_O     735232   // E0,Er,Ei (3*4096)
#define TB_O     747520
#define BT_O     751616
#define RSTK_O   755712   // R_t, t=0..2 (3*4096)
#define LCT_O    772096   // L_t as [t][k][i], t=0..2 (3*4096)
#define WG_O     788480
#define XG_O     792576
#define WS_NEED  796672

__device__ __forceinline__ float aload(const float* p) {
  return __hip_atomic_load(p, __ATOMIC_RELAXED, __HIP_MEMORY_SCOPE_AGENT);
}
__device__ __forceinline__ void astore(float* p, float v) {
  __hip_atomic_store(p, v, __ATOMIC_RELAXED, __HIP_MEMORY_SCOPE_AGENT);
}

// ---- fetch-add barrier + atomic reduction (R5/R7-proven fast) ----
__device__ __forceinline__ void gbar(int* cnt, int target) {
  __syncthreads();
  if (threadIdx.x == 0) {
    __hip_atomic_fetch_add(cnt, 1, __ATOMIC_ACQ_REL, __HIP_MEMORY_SCOPE_AGENT);
    while (__hip_atomic_load(cnt, __ATOMIC_ACQUIRE, __HIP_MEMORY_SCOPE_AGENT) < target) {
      __builtin_amdgcn_s_sleep(2);
    }
  }
  __syncthreads();
}
__device__ __forceinline__ void red_atomic(float v, float* red, float* dst) {
  int tid = threadIdx.x;
  red[tid] = v;
  __syncthreads();
  if (tid < 128) red[tid] += red[tid + 128];
  __syncthreads();
  if (tid < 64) {
    float s = red[tid] + red[tid + 64];
#pragma unroll
    for (int o = 32; o > 0; o >>= 1) s += __shfl_down(s, o, 64);
    if (tid == 0) atomicAdd(dst, s);
  }
  __syncthreads();
}

// ---- plain-memory LDS staging + 64x64 GEMM helpers ----
__device__ __forceinline__ void stageN(float* dst, const float* src) {
  for (int e = threadIdx.x; e < 4096; e += 256)
    dst[(e >> 6) * 65 + (e & 63)] = src[e];
}
__device__ __forceinline__ void stageT(float* dst, const float* src) {
  for (int e = threadIdx.x; e < 4096; e += 256)
    dst[(e & 63) * 65 + (e >> 6)] = src[e];
}
__device__ __forceinline__ void mm65(const float* Ls, const float* Rs, float* D) {
  for (int e = threadIdx.x; e < 4096; e += 256) {
    int i = e >> 6, j = e & 63;
    float a0 = 0.f, a1 = 0.f;
#pragma unroll 8
    for (int t = 0; t < 64; t += 2) {
      a0 = fmaf(Ls[i * 65 + t], Rs[t * 65 + j], a0);
      a1 = fmaf(Ls[i * 65 + t + 1], Rs[(t + 1) * 65 + j], a1);
    }
    D[e] = a0 + a1;
  }
}
__device__ void mmNN_s(const float* L, const float* R, float* D, float* sm) {
  stageN(sm, L); stageN(sm + 4160, R);
  __syncthreads();
  mm65(sm, sm + 4160, D);
}
__device__ void mmNT_s(const float* L, const float* R, float* D, float* sm) {
  stageN(sm, L); stageT(sm + 4160, R);
  __syncthreads();
  mm65(sm, sm + 4160, D);
}

// ---- 64x64 SPD Cholesky + explicit L^-1 (plain memory) ----
__device__ void chol_inv(const float* S, float* Li, float* sm) {
  float (*M)[65] = (float (*)[65])sm;
  float (*T)[65] = (float (*)[65])(sm + 64 * 65);
  int tid = threadIdx.x;
  for (int e = tid; e < 4096; e += 256) {
    M[e >> 6][e & 63] = S[e];
    T[e >> 6][e & 63] = 0.f;
  }
  __syncthreads();
  for (int j = 0; j < 64; ++j) {
    float pv = M[j][j];
    __syncthreads();
    float sc = rsqrtf(pv);
    if (tid < 64 - j) M[j + tid][j] *= sc;
    __syncthreads();
    int m = 63 - j, c2 = (m * (m + 1)) >> 1;
    for (int e = tid; e < c2; e += 256) {
      int rp = (int)((sqrtf(8.f * (float)e + 1.f) - 1.f) * 0.5f);
      while (((rp + 1) * (rp + 2)) >> 1 <= e) ++rp;
      while ((rp * (rp + 1)) >> 1 > e) --rp;
      int cp = e - ((rp * (rp + 1)) >> 1);
      int r = j + 1 + rp, c = j + 1 + cp;
      M[r][c] = fmaf(-M[r][j], M[c][j], M[r][c]);
    }
    __syncthreads();
  }
  if (tid < 64) {
    int c = tid;
    T[c][c] = 1.f / M[c][c];
    for (int r = c + 1; r < 64; ++r) {
      float s = 0.f;
      for (int t = c; t < r; ++t) s = fmaf(M[r][t], T[t][c], s);
      T[r][c] = -s / M[r][r];
    }
  }
  __syncthreads();
  for (int e = tid; e < 4096; e += 256) Li[e] = T[e >> 6][e & 63];
}

// ================= K1: proj partials (80) + H (2) + sv/ctrl (1) =================
__global__ __launch_bounds__(256) void k1_kernel(const float* fx, const float* fy,
                                                 const float* ex, const float* ey,
                                                 const float* Px, const float* Py,
                                                 const float* My, float* W) {
  __shared__ float sm[8064];
  int tid = threadIdx.x, blk = blockIdx.x;
  if (blk < 80) {
    int mat = (blk >= 40), seg = mat ? (blk - 40) : blk;
    const float* P = (mat ? Py : Px);
    const float* f = (mat ? fy : fx);
    int v0 = seg * 125;
    // stage P[64][125] -> sm[r*126+vv]
    for (int e = tid; e < 8000; e += 256) {
      int rr = e / 125, vv = e - rr * 125;
      sm[rr * 126 + vv] = P[rr * NV + v0 + vv];
    }
    __syncthreads();
    int rg = (tid >> 5) << 3;   // 8 rows
    int cq = (tid & 31) << 2;   // 4 cols
    float acc[8][4];
#pragma unroll
    for (int u = 0; u < 8; ++u)
#pragma unroll
      for (int v = 0; v < 4; ++v) acc[u][v] = 0.f;
    for (int v5 = 0; v5 < 125; v5 += 5) {
      float4 fv[5];
#pragma unroll
      for (int q = 0; q < 5; ++q)
        fv[q] = *(const float4*)(f + (size_t)(v0 + v5 + q) * 128 + cq);
#pragma unroll
      for (int q = 0; q < 5; ++q) {
#pragma unroll
        for (int u = 0; u < 8; ++u) {
          float pv = sm[(rg + u) * 126 + v5 + q];
          acc[u][0] = fmaf(pv, fv[q].x, acc[u][0]);
          acc[u][1] = fmaf(pv, fv[q].y, acc[u][1]);
          acc[u][2] = fmaf(pv, fv[q].z, acc[u][2]);
          acc[u][3] = fmaf(pv, fv[q].w, acc[u][3]);
        }
      }
    }
    float* O = W + PART_O + (size_t)blk * 8192;
#pragma unroll
    for (int u = 0; u < 8; ++u) {
      float4 o = make_float4(acc[u][0], acc[u][1], acc[u][2], acc[u][3]);
      *(float4*)(O + (rg + u) * 128 + cq) = o;
    }
  } else if (blk < 82) {
    // H = My^T My (two halves), My staged
    for (int e = tid; e < 4096; e += 256) sm[(e >> 6) * 65 + (e & 63)] = My[e];
    __syncthreads();
    int base = (blk - 80) * 2048;
    for (int e = tid; e < 2048; e += 256) {
      int i = (base + e) >> 6, j = (base + e) & 63;
      float a0 = 0.f, a1 = 0.f;
#pragma unroll 8
      for (int t = 0; t < 64; t += 2) {
        a0 = fmaf(sm[t * 65 + i], sm[t * 65 + j], a0);
        a1 = fmaf(sm[(t + 1) * 65 + i], sm[(t + 1) * 65 + j], a1);
      }
      W[H_O + base + e] = a0 + a1;
    }
  } else {
    // sv + zero ctrl
    if (tid < 64) {
      float vx = ex[tid], vy = ey[tid];
      float m = fmaxf(vx, vy);
#pragma unroll
      for (int o = 32; o > 0; o >>= 1) m = fmaxf(m, __shfl_xor(m, o, 64));
      float g1 = sqrtf(vx / m), g2 = sqrtf(vy / m);   // GAMMA = 0.5
      float d1 = 1.f / fmaf(g1, g1, 1.f), d2 = 1.f / fmaf(g2, g2, 1.f);
      W[SV_O + tid] = g1 * d1;          // r1r
      W[SV_O + 64 + tid] = d1;          // r1i
      W[SV_O + 128 + tid] = g2 * d2;    // d2r
      W[SV_O + 192 + tid] = d2;         // d2i
    }
    for (int e = tid; e < 512; e += 256) ((int*)(W + CTRL_O))[e] = 0;
  }
}

// ================= K2: Ahat (8) + B0 (8) + chol(H) (1) + Q* (3) =================
__global__ __launch_bounds__(256) void k2_kernel(const float* Mx, float* W) {
  __shared__ float sm[8448];
  int tid = threadIdx.x, blk = blockIdx.x;
  if (blk < 8) {
    // sum A partials for 16 cols, then Ahat = Mx^T (sumA)
    int c0 = blk * 16;
    float* ssum = sm;          // [64][17]
    float* mxs = sm + 1088;    // [64][65]
    for (int e = tid; e < 4096; e += 256) mxs[(e >> 6) * 65 + (e & 63)] = Mx[e];
    for (int e = tid; e < 1024; e += 256) {
      int t = e >> 4, cl = e & 15;
      float s = 0.f;
      for (int p = 0; p < 40; ++p) s += W[PART_O + (size_t)p * 8192 + t * 128 + c0 + cl];
      ssum[t * 17 + cl] = s;
    }
    __syncthreads();
    for (int e = tid; e < 1024; e += 256) {
      int i = e >> 4, cl = e & 15;
      float a0 = 0.f, a1 = 0.f;
#pragma unroll 8
      for (int t = 0; t < 64; t += 2) {
        a0 = fmaf(mxs[t * 65 + i], ssum[t * 17 + cl], a0);
        a1 = fmaf(mxs[(t + 1) * 65 + i], ssum[(t + 1) * 17 + cl], a1);
      }
      W[AH_O + i * 128 + c0 + cl] = a0 + a1;
    }
  } else if (blk < 16) {
    int base = (blk - 8) * 1024;
    for (int e = tid; e < 1024; e += 256) {
      float s = 0.f;
      for (int p = 0; p < 40; ++p) s += W[PART_O + (size_t)(40 + p) * 8192 + base + e];
      W[B0_O + base + e] = s;
    }
  } else if (blk == 16) {
    chol_inv(W + H_O, W + LIH_O, sm);
  } else {
    if (tid < 256) sm[tid] = W[SV_O + tid];
    __syncthreads();
    int t = blk - 17;
    for (int e = tid; e < 4096; e += 256) {
      int k = e >> 6, b = e & 63;
      float h = W[H_O + e], v;
      if (t == 0) v = h * (sm[128 + k] * sm[128 + b] + sm[192 + k] * sm[192 + b]);
      else if (t == 1) v = h * (sm[128 + k] + sm[128 + b]);
      else v = h * (sm[192 + k] + sm[192 + b]);
      W[Q0_O + t * 4096 + e] = v;
    }
  }
}

// ================= K3: E (4) + Z2 (4) + U* (3) =================
__global__ __launch_bounds__(256) void k3_kernel(float* W) {
  __shared__ float sm[10496];
  int tid = threadIdx.x, blk = blockIdx.x;
  if (blk < 4) {
    // E[i][j] = sum_c Ahat[i][c] Ahat[j][c] (+ LMB diag), i in [blk*16, +16)
    for (int e = tid; e < 8192; e += 256) {
      int i = e >> 7, c = e & 127;
      sm[c * 65 + i] = W[AH_O + e];     // AhT[c][i]
    }
    __syncthreads();
    int i0 = blk * 16;
    for (int e = tid; e < 1024; e += 256) {
      int i = i0 + (e >> 6), j = e & 63;
      float a0 = 0.f, a1 = 0.f;
#pragma unroll 8
      for (int c = 0; c < 128; c += 2) {
        a0 = fmaf(sm[c * 65 + i], sm[c * 65 + j], a0);
        a1 = fmaf(sm[(c + 1) * 65 + i], sm[(c + 1) * 65 + j], a1);
      }
      float acc = a0 + a1;
      if (i == j) {
        float a = W[SV_O + i], b = W[SV_O + 64 + i];
        acc += LMB * (a * a + b * b);
      }
      W[E_O + i * 64 + j] = acc;
    }
  } else if (blk < 8) {
    // Z2 = Ahat B0^T, rows [ (blk-4)*16, +16 )
    int i0 = (blk - 4) * 16;
    for (int e = tid; e < 8192; e += 256) {
      int j = e >> 7, c = e & 127;
      sm[c * 65 + j] = W[B0_O + e];     // B0T[c][j]
    }
    for (int e = tid; e < 2048; e += 256) {
      int il = e >> 7, c = e & 127;
      sm[8320 + c * 17 + il] = W[AH_O + (i0 + il) * 128 + c];
    }
    __syncthreads();
    for (int e = tid; e < 1024; e += 256) {
      int il = e >> 6, j = e & 63;
      float a0 = 0.f, a1 = 0.f;
#pragma unroll 8
      for (int c = 0; c < 128; c += 2) {
        a0 = fmaf(sm[8320 + c * 17 + il], sm[c * 65 + j], a0);
        a1 = fmaf(sm[8320 + (c + 1) * 17 + il], sm[(c + 1) * 65 + j], a1);
      }
      W[Z2_O + (i0 + il) * 64 + j] = a0 + a1;
    }
  } else {
    int t = blk - 8;
    mmNN_s(W + LIH_O, W + Q0_O + t * 4096, W + U0_O + t * 4096, sm);
  }
}

// ================= K4: chol(E) (0) + RH (1) + QT* (2-4) =================
__global__ __launch_bounds__(256) void k4_kernel(float* W) {
  __shared__ float sm[8448];
  int blk = blockIdx.x;
  if (blk == 0) chol_inv(W + E_O, W + LIE_O, sm);
  else if (blk == 1) mmNN_s(W + Z2_O, W + H_O, W + RH_O, sm);
  else mmNT_s(W + U0_O + (blk - 2) * 4096, W + LIH_O, W + QT0_O + (blk - 2) * 4096, sm);
}

// ================= K5: TB (0) + E0 (1) + Er/Ei (2-3) =================
__global__ __launch_bounds__(256) void k5_kernel(float* W) {
  __shared__ float sm[8448];
  int tid = threadIdx.x, blk = blockIdx.x;
  if (blk == 0) mmNN_s(W + LIE_O, W + RH_O, W + TB_O, sm);
  else if (blk == 1) mmNT_s(W + LIE_O, W + LIE_O, W + E0_O, sm);
  else {
    __shared__ float dv[64];
    if (tid < 64) dv[tid] = W[SV_O + ((blk == 2) ? tid : 64 + tid)];
    stageN(sm, W + LIE_O);
    __syncthreads();
    for (int e = tid; e < 4096; e += 256) {
      int j = e >> 6, k = e & 63;
      sm[4160 + k * 65 + j] = sm[j * 65 + k] * dv[k];
    }
    __syncthreads();
    mm65(sm, sm + 4160, W + E0_O + (blk - 1) * 4096);
  }
}

// ================= K6: BT (0) + RSTK (1-2) + LCT (3-4) =================
__global__ __launch_bounds__(256) void k6_kernel(float* W) {
  __shared__ float sm[8448];
  int tid = threadIdx.x, blk = blockIdx.x;
  if (blk == 0) mmNT_s(W + TB_O, W + LIH_O, W + BT_O, sm);
  else if (blk <= 2) {
    int nt = (blk == 1) ? 2 : 1;
    for (int tt = 0; tt < nt; ++tt) {
      int t = (blk - 1) * 2 + tt;
      stageN(sm, W + QT0_O + t * 4096);
      __syncthreads();
      for (int e = tid; e < 4096; e += 256) {
        int a = e >> 6, b = e & 63;
        W[RSTK_O + t * 4096 + e] = 0.5f * (sm[a * 65 + b] + sm[b * 65 + a]);
      }
      __syncthreads();
    }
  } else {
    int nt = (blk == 3) ? 2 : 1;
    for (int tt = 0; tt < nt; ++tt) {
      int t = (blk - 3) * 2 + tt;
      float sgn = (t == 0) ? LMB : -LMB;
      stageN(sm, W + E0_O + t * 4096);
      __syncthreads();
      for (int e = tid; e < 4096; e += 256) {
        int k = e >> 6, i = e & 63;
        W[LCT_O + t * 4096 + e] = sgn * 0.5f * (sm[k * 65 + i] + sm[i * 65 + k]);
      }
      __syncthreads();
    }
  }
}

// ---- apply: At(Y) = Y + sum_{t=0..2} L_t (Y R_t); Y in pT[col][row] ----
__device__ __forceinline__ float at_apply3(const float (*pT)[68], const float* Rown,
                                           float* Tt, const float* LCT,
                                           int lane, int wv, int jown) {
  if (wv >= 1) {
    const float* R0 = Rown + (wv - 1) * 256;
    float a0 = 0.f, a1 = 0.f, a2 = 0.f, a3 = 0.f;
    for (int m = 0; m < 64; ++m) {
      float pv = pT[m][lane];
      a0 = fmaf(pv, R0[m], a0);
      a1 = fmaf(pv, R0[64 + m], a1);
      a2 = fmaf(pv, R0[128 + m], a2);
      a3 = fmaf(pv, R0[192 + m], a3);
    }
    Tt[0 * 192 + (wv - 1) * 64 + lane] = a0;
    Tt[1 * 192 + (wv - 1) * 64 + lane] = a1;
    Tt[2 * 192 + (wv - 1) * 64 + lane] = a2;
    Tt[3 * 192 + (wv - 1) * 64 + lane] = a3;
  }
  __syncthreads();
  const float* Lc = LCT + lane;
  const float* Tw = Tt + wv * 192;
  float b0 = 0.f, b1 = 0.f, b2 = 0.f, b3 = 0.f;
  for (int tk = 0; tk < 192; tk += 4) {
    b0 = fmaf(Lc[(tk + 0) * 64], Tw[tk + 0], b0);
    b1 = fmaf(Lc[(tk + 1) * 64], Tw[tk + 1], b1);
    b2 = fmaf(Lc[(tk + 2) * 64], Tw[tk + 2], b2);
    b3 = fmaf(Lc[(tk + 3) * 64], Tw[tk + 3], b3);
  }
  return pT[jown][lane] + (b0 + b1) + (b2 + b3);
}

// ================= K7: pipelined Jacobi-PCG (GV) + finish =================
__global__ __launch_bounds__(256) void cg_kernel(const float* Mx, float* W, float* out) {
  __shared__ float sm[8704];
  __shared__ float red[256];
  __shared__ float scal[3];
  __shared__ float sLd[192], sRd[192];
  int tid = threadIdx.x, blk = blockIdx.x;
  int lane = tid & 63, wv = tid >> 6;
  int j0 = blk * 4, jown = j0 + wv;
  float (*pT)[68] = (float (*)[68])sm;
  float* Rown = sm + 4352;
  float* Tt = sm + 5120;
  const float* BT = W + BT_O;
  const float* RSTK = W + RSTK_O;
  const float* LCT = W + LCT_O;
  float* wg = W + WG_O;
  int* cnt = (int*)(W + CTRL_O);
  float* RZ = W + CTRL_O + 64;
  float* PQ = W + CTRL_O + 264;

  // stage own R rows + diagonal vectors
  for (int e = tid; e < 768; e += 256) {
    int t = e >> 8, jl = (e >> 6) & 3, m = e & 63;
    Rown[t * 256 + jl * 64 + m] = RSTK[(t * 64 + j0 + jl) * 64 + m];
  }
  if (tid < 192) {
    int t = tid >> 6, i = tid & 63;
    sLd[tid] = LCT[t * 4096 + i * 64 + i];
    sRd[tid] = RSTK[t * 4096 + i * 64 + i];
  }
  __syncthreads();
  float invd = 1.f / (1.f + sLd[lane] * sRd[jown] + sLd[64 + lane] * sRd[64 + jown] +
                      sLd[128 + lane] * sRd[128 + jown]);
  // u0 = M^-1 b (full, locally computable), w0 = At(u0)
  for (int u = 0; u < 16; ++u) {
    int g = u * 256 + tid;               // g = col*64+row
    int col = g >> 6, row = g & 63;
    float den = 1.f + sLd[row] * sRd[col] + sLd[64 + row] * sRd[64 + col] +
                sLd[128 + row] * sRd[128 + col];
    pT[col][row] = BT[row * 64 + col] / den;
  }
  __syncthreads();
  float u_l = pT[jown][lane];
  float w_l = at_apply3(pT, Rown, Tt, LCT, lane, wv, jown);
  float r_l = BT[lane * 64 + jown];
  float m_l = invd * w_l;
  astore(&wg[jown * 64 + lane], m_l);
  red_atomic(r_l * u_l, red, &RZ[0]);
  red_atomic(w_l * u_l, red, &PQ[0]);
  int bt = 0;
  gbar(cnt, (++bt) * NBLK);

  float p_l = 0.f, q_l = 0.f, z_l = 0.f, s_l = 0.f, x_l = 0.f;
  float gprev = 1.f, aprev = 1.f, g0 = 1.f;
  for (int j = 0; j < MAXIT; ++j) {
    if (tid == 0) {
      scal[0] = aload(&RZ[j]);
      scal[1] = aload(&PQ[j]);
      scal[2] = aload(&RZ[0]);
    }
    __syncthreads();
    float gj = scal[0], dj = scal[1];
    if (j == 0) g0 = scal[2];
    if (j > 0 && fabsf(gj) < TOL * fabsf(g0)) break;
    float bj = (j == 0) ? 0.f : gj / gprev;
    float aj = (j == 0) ? gj / dj : gj / (dj - bj * gj / aprev);
    // n = At(m): read full m
    for (int u = 0; u < 16; ++u) {
      int g = u * 256 + tid;
      pT[g >> 6][g & 63] = aload(&wg[g]);
    }
    __syncthreads();
    float n_l = at_apply3(pT, Rown, Tt, LCT, lane, wv, jown);
    z_l = fmaf(bj, z_l, n_l);
    q_l = fmaf(bj, q_l, m_l);
    s_l = fmaf(bj, s_l, w_l);
    p_l = fmaf(bj, p_l, u_l);
    x_l = fmaf(aj, p_l, x_l);
    r_l = fmaf(-aj, s_l, r_l);
    u_l = fmaf(-aj, q_l, u_l);
    w_l = fmaf(-aj, z_l, w_l);
    m_l = invd * w_l;
    astore(&wg[jown * 64 + lane], m_l);
    red_atomic(r_l * u_l, red, &RZ[j + 1]);
    red_atomic(w_l * u_l, red, &PQ[j + 1]);
    gprev = gj; aprev = aj;
    gbar(cnt, (++bt) * NBLK);
  }
  astore(&W[XG_O + jown * 64 + lane], x_l);   // Y col-major
  gbar(cnt, (++bt) * NBLK);

  // ---- finish (block 0): out = (Mx LiE^T Y LiH)^T ----
  if (blk == 0) {
    float* Ys = sm;           // [64][65]
    float* Ms2 = sm + 4160;   // [64][65]
    for (int e = tid; e < 4096; e += 256) Ys[(e >> 6) * 65 + (e & 63)] = aload(W + XG_O + e);
    for (int e = tid; e < 4096; e += 256) Ms2[(e >> 6) * 65 + (e & 63)] = W[LIE_O + e];
    __syncthreads();
    for (int e = tid; e < 4096; e += 256) {   // V1 = LiE^T Y  (Ys[j][i] = Y[i][j])
      int t = e >> 6, b = e & 63;
      float acc = 0.f;
#pragma unroll 8
      for (int a = 0; a < 64; ++a) acc = fmaf(Ms2[a * 65 + t], Ys[b * 65 + a], acc);
      W[WG_O + t * 64 + b] = acc;
    }
    __syncthreads();
    for (int e = tid; e < 4096; e += 256) Ys[(e >> 6) * 65 + (e & 63)] = W[WG_O + e];
    for (int e = tid; e < 4096; e += 256) Ms2[(e >> 6) * 65 + (e & 63)] = W[LIH_O + e];
    __syncthreads();
    for (int e = tid; e < 4096; e += 256) {   // WH = V1 LiH
      int t = e >> 6, c = e & 63;
      float acc = 0.f;
#pragma unroll 8
      for (int b = 0; b < 64; ++b) acc = fmaf(Ys[t * 65 + b], Ms2[b * 65 + c], acc);
      W[WG_O + t * 64 + c] = acc;
    }
    __syncthreads();
    for (int e = tid; e < 4096; e += 256) Ys[(e >> 6) * 65 + (e & 63)] = W[WG_O + e];
    for (int e = tid; e < 4096; e += 256) Ms2[(e & 63) * 65 + (e >> 6)] = Mx[e];
    __syncthreads();
    for (int e = tid; e < 4096; e += 256) {   // out[r][c] = sum_t Mx[c][t] WH[t][r]
      int r = e >> 6, c = e & 63;
      float acc = 0.f;
#pragma unroll 8
      for (int t = 0; t < 64; ++t) acc = fmaf(Ms2[t * 65 + c], Ys[t * 65 + r], acc);
      out[e] = acc;
    }
  }
}

extern "C" void kernel_launch(void* const* d_in, const int* in_sizes, int n_in,
                              void* d_out, int out_size, void* d_ws, size_t ws_size,
                              hipStream_t stream) {
  const float* fx = (const float*)d_in[0];
  const float* fy = (const float*)d_in[1];
  const float* ex = (const float*)d_in[2];
  const float* ey = (const float*)d_in[3];
  const float* Px = (const float*)d_in[4];
  const float* Py = (const float*)d_in[5];
  const float* Mx = (const float*)d_in[6];
  const float* My = (const float*)d_in[7];
  float* out = (float*)d_out;
  float* W = (float*)d_ws;

  if (ws_size < (size_t)WS_NEED * sizeof(float)) {
    hipMemsetAsync(d_out, 0, (size_t)out_size * sizeof(float), stream);
    return;
  }

  k1_kernel<<<83, 256, 0, stream>>>(fx, fy, ex, ey, Px, Py, My, W);
  k2_kernel<<<20, 256, 0, stream>>>(Mx, W);
  k3_kernel<<<11, 256, 0, stream>>>(W);
  k4_kernel<<<5, 256, 0, stream>>>(W);
  k5_kernel<<<4, 256, 0, stream>>>(W);
  k6_kernel<<<5, 256, 0, stream>>>(W);
  cg_kernel<<<NBLK, 256, 0, stream>>>(Mx, W, out);
}